// Round 6
// baseline (1176.466 us; speedup 1.0000x reference)
//
#include <hip/hip_runtime.h>

// DiffusionBlock: 20 steps of depthwise 3x3 stencil, reflect padding, on
// (16,2,1024,1024) fp32 — SINGLE launch, all 20 steps fused, SCALAR math.
//
// LDS-free register-rolling pipeline (5-point cross stencil: corner weights
// are exactly 0; w_l==w_r, w_t==w_b):
//   u_{s+1}[r] = w01*(u_s[r-1]+u_s[r+1]) + w10*(left+right) + w11*u_s[r]
// Each wave owns a 256-col swath (float4/lane), marches down rows keeping a
// 2-row register window per fused stage (40 NAMED float4 registers — never
// arrays). Horizontal halo via DPP wave_shr:1/wave_shl:1. Column mirror via
// per-lane cndmask; row mirror exact in gated head/tail phases.
//
// ROUND 6: round 5 showed packed fp32 (ext_vector) REGRESSES: VOP3P needs
// even-aligned pairs -> mov-shuffles + spill (WRITE_SIZE +21MB, 167us vs
// 132us scalar). That also re-explains round 4's KF=20 blowup: paired banks
// fragment the allocator. So: KF=20 single launch with SCALAR float4 banks
// (~195 VGPR, no pairing), which deletes the 131MB intermediate write +
// 103MB re-read and the ~120us inter-dispatch gap. Plus: runtime-uniform
// specialization for the actual weights (w11 = 1-2hx-2hy = 0, w01==w10) ->
// u' = (up+down+left+right)*w01, 20 VALU/stage instead of 24 (generic
// template fallback kept for semantic honesty).
// TRIPWIRE: WRITE_SIZE must be ~131072 KB; if larger, spills returned.

#define IMG  1024
#define KF   20           // fused steps (all of them)
#define RB   64           // output rows per band
#define LPAD 20           // left extension cols (>= KF, multiple of 4)
#define SW   216          // useful cols per swath (256 - 2*LPAD)
#define NSW  5            // 5*216 = 1080 >= 1024
#define NB   (IMG/RB)     // 16 bands
#define NPL  32           // planes = 16 batch * 2 ch
#define WPL  (NB*NSW)     // 80 waves per plane
#define NWAVES (NPL*WPL)  // 2560

__device__ __forceinline__ float dpp_left(float v) {   // lane i <- lane i-1 (wave_shr:1)
    return __int_as_float(__builtin_amdgcn_update_dpp(
        __float_as_int(v), __float_as_int(v), 0x138, 0xf, 0xf, false));
}
__device__ __forceinline__ float dpp_right(float v) {  // lane i <- lane i+1 (wave_shl:1)
    return __int_as_float(__builtin_amdgcn_update_dpp(
        __float_as_int(v), __float_as_int(v), 0x130, 0xf, 0xf, false));
}

// One fused stage: consumes C (= u_{j-1}[f+1]), bank OV (= u_{j-1}[f-1]),
// bank NV (= u_{j-1}[f]); produces u_j[f] into C, rotates OV <- old C.
// GEN=1 adds uniform activity gating + row-mirror patches (head/tail only).
// FAST (constexpr): weights are {w11==0, w01==w10} -> sum-of-4 * w01.
#define STAGE(jj, OV, NV, GEN)                                               \
    {                                                                        \
        float4 Cn; bool pr = true;                                           \
        const int f = _r - (jj);                                             \
        bool act = true;                                                     \
        if (GEN) {                                                           \
            const int lo = max(ob - KF + (jj), 0);                           \
            const int hi = min(ob + RB - 1 + KF - (jj), IMG - 1);            \
            act = (f >= lo) && (f <= hi);                                    \
        }                                                                    \
        if (act) {                                                           \
            const float4 mid = NV;                                           \
            float4 vs;                                                       \
            if (GEN && f == 0) {               /* u[-1] = u[1] = C */        \
                vs.x = C.x + C.x; vs.y = C.y + C.y;                          \
                vs.z = C.z + C.z; vs.w = C.w + C.w;                          \
            } else if (GEN && f == IMG - 1) {  /* u[N] = u[N-2] = OV */      \
                vs.x = OV.x + OV.x; vs.y = OV.y + OV.y;                      \
                vs.z = OV.z + OV.z; vs.w = OV.w + OV.w;                      \
            } else {                                                         \
                vs.x = OV.x + C.x; vs.y = OV.y + C.y;                        \
                vs.z = OV.z + C.z; vs.w = OV.w + C.w;                        \
            }                                                                \
            float lf = dpp_left(mid.w);                                      \
            float rg = dpp_right(mid.x);                                     \
            if (is_cL) lf = mid.y;             /* col 0: mirror col 1 */     \
            if (is_cR) rg = mid.z;             /* col 1023: mirror 1022 */   \
            const float h0 = lf    + mid.y;                                  \
            const float h1 = mid.x + mid.z;                                  \
            const float h2 = mid.y + mid.w;                                  \
            const float h3 = mid.z + rg;                                     \
            if constexpr (FAST) {                                            \
                Cn.x = (vs.x + h0) * w01;                                    \
                Cn.y = (vs.y + h1) * w01;                                    \
                Cn.z = (vs.z + h2) * w01;                                    \
                Cn.w = (vs.w + h3) * w01;                                    \
            } else {                                                         \
                Cn.x = vs.x*w01 + h0*w10 + mid.x*w11;                        \
                Cn.y = vs.y*w01 + h1*w10 + mid.y*w11;                        \
                Cn.z = vs.z*w01 + h2*w10 + mid.z*w11;                        \
                Cn.w = vs.w*w01 + h3*w10 + mid.w*w11;                        \
            }                                                                \
        } else { pr = false; Cn = C; }                                       \
        if (prod) { OV = C; }                                                \
        C = Cn; prod = GEN ? pr : true;                                      \
    }

// One pipeline advance at absolute input row rv. PF (p0/p1) holds row rv,
// reloaded with row rv+2. Bank names passed explicitly per stage.
#define STEPN(rv, PF, GEN,                                                   \
              O0,N0,O1,N1,O2,N2,O3,N3,O4,N4,O5,N5,O6,N6,O7,N7,O8,N8,O9,N9,  \
              O10,N10,O11,N11,O12,N12,O13,N13,O14,N14,O15,N15,O16,N16,      \
              O17,N17,O18,N18,O19,N19)                                       \
    do {                                                                     \
        const int _r = (rv);                                                 \
        float4 C = PF;                                                       \
        if (_r + 2 <= in_hi)                                                 \
            PF = *(const float4*)(lp + (size_t)(_r + 2) * IMG);              \
        bool prod = GEN ? (_r <= in_hi) : true;                              \
        STAGE(1,  O0,  N0,  GEN)                                             \
        STAGE(2,  O1,  N1,  GEN)                                             \
        STAGE(3,  O2,  N2,  GEN)                                             \
        STAGE(4,  O3,  N3,  GEN)                                             \
        STAGE(5,  O4,  N4,  GEN)                                             \
        STAGE(6,  O5,  N5,  GEN)                                             \
        STAGE(7,  O6,  N6,  GEN)                                             \
        STAGE(8,  O7,  N7,  GEN)                                             \
        STAGE(9,  O8,  N8,  GEN)                                             \
        STAGE(10, O9,  N9,  GEN)                                             \
        STAGE(11, O10, N10, GEN)                                             \
        STAGE(12, O11, N11, GEN)                                             \
        STAGE(13, O12, N12, GEN)                                             \
        STAGE(14, O13, N13, GEN)                                             \
        STAGE(15, O14, N14, GEN)                                             \
        STAGE(16, O15, N15, GEN)                                             \
        STAGE(17, O16, N16, GEN)                                             \
        STAGE(18, O17, N17, GEN)                                             \
        STAGE(19, O18, N18, GEN)                                             \
        STAGE(20, O19, N19, GEN)                                             \
        if ((!GEN || prod) && st_ok)                                         \
            *(float4*)(op + (size_t)(_r - KF) * IMG) = C;                    \
    } while (0)

#define STEP_E(rv, GEN) STEPN(rv, p0, GEN,                                   \
    a0,b0,a1,b1,a2,b2,a3,b3,a4,b4,a5,b5,a6,b6,a7,b7,a8,b8,a9,b9,             \
    a10,b10,a11,b11,a12,b12,a13,b13,a14,b14,a15,b15,a16,b16,a17,b17,         \
    a18,b18,a19,b19)
#define STEP_O(rv, GEN) STEPN(rv, p1, GEN,                                   \
    b0,a0,b1,a1,b2,a2,b3,a3,b4,a4,b5,a5,b6,a6,b7,a7,b8,a8,b9,a9,             \
    b10,a10,b11,a11,b12,a12,b13,a13,b14,a14,b15,a15,b16,a16,b17,a17,         \
    b18,a18,b19,a19)

template <bool FAST>
__device__ __forceinline__ void run_pipeline(
    const float* __restrict__ lp, float* __restrict__ op,
    float w01, float w10, float w11,
    int ob, bool is_cL, bool is_cR, bool st_ok,
    int r_lo, int in_hi, int r_hi, int head_end, int st_end)
{
    // 2-row banks for stages u_0..u_19 — NAMED registers (never an array).
    float4 a0{},a1{},a2{},a3{},a4{},a5{},a6{},a7{},a8{},a9{};
    float4 a10{},a11{},a12{},a13{},a14{},a15{},a16{},a17{},a18{},a19{};
    float4 b0{},b1{},b2{},b3{},b4{},b5{},b6{},b7{},b8{},b9{};
    float4 b10{},b11{},b12{},b13{},b14{},b15{},b16{},b17{},b18{},b19{};

    float4 p0, p1;                          // distance-2 row prefetch slots
    p0 = *(const float4*)(lp + (size_t)r_lo * IMG);
    p1 = *(const float4*)(lp + (size_t)(r_lo + 1) * IMG);

    // Phase lengths are all even and preserve the even/odd role alternation.
    // unroll(disable): bodies are already ~600-inst straight-line blocks and
    // iterations are serially dependent — unrolling is pure code-size.
    #pragma clang loop unroll(disable)
    for (int r = r_lo; r <= head_end; r += 2) {
        STEP_E(r,     1);
        STEP_O(r + 1, 1);
    }
    #pragma clang loop unroll(disable)
    for (int r = head_end + 1; r <= st_end; r += 2) {
        STEP_E(r,     0);
        STEP_O(r + 1, 0);
    }
    #pragma clang loop unroll(disable)
    for (int r = st_end + 1; r <= r_hi; r += 2) {
        STEP_E(r,     1);
        STEP_O(r + 1, 1);
    }
}

__global__ __launch_bounds__(64, 2) void diff20(
    const float* __restrict__ src, float* __restrict__ dst,
    const float* __restrict__ wt)
{
    const int lane  = threadIdx.x;          // 64-thread block == one wave
    const int gw    = blockIdx.x;
    const int plane = gw / WPL;
    const int rem   = gw - plane * WPL;
    const int band  = rem / NSW;
    const int sw    = rem - band * NSW;

    const int ob  = band * RB;              // first output row of this band
    const int uc0 = sw * SW;                // first useful col of this swath
    const int c0  = uc0 - LPAD + 4 * lane;  // this lane's first col (may be <0)
    const int cld = min(max(c0, 0), IMG - 4); // clamped load col (garbage ok)

    const float* __restrict__ lp = src + (size_t)plane * IMG * IMG + cld;
    float* __restrict__       op = dst + (size_t)plane * IMG * IMG + cld;

    const float* w9 = wt + (size_t)(plane & 1) * 9;
    const float w01 = w9[1];   // vertical weight (== w9[7])
    const float w10 = w9[3];   // horizontal weight (== w9[5])
    const float w11 = w9[4];   // center weight (corners are 0)

    const bool is_cL  = (c0 == 0);          // lane's .x is image col 0
    const bool is_cR  = (c0 == IMG - 4);    // lane's .w is image col 1023
    const bool st_ok  = (c0 >= uc0) && (c0 < uc0 + SW) && (c0 <= IMG - 4);

    const int r_lo  = max(ob - KF, 0);
    const int in_hi = min(ob + RB - 1 + KF, IMG - 1);
    const int r_hi  = ob + RB - 1 + KF;     // last pipeline iteration
    const int head_end = r_lo + 2 * KF - 1; // generic head (2*KF steps, even)
    const int st_end   = min(r_hi, IMG - 1);// steady end; tail drains

    // Uniform specialization: actual weights have w11 == 0 (TAU=0.25,
    // H1=H2=1 -> 1-2hx-2hy = 0) and w01 == w10 == 0.25. Exact fp compare is
    // safe (values are exact). Generic path kept as fallback.
    if (w11 == 0.0f && w01 == w10) {
        run_pipeline<true>(lp, op, w01, w10, w11, ob, is_cL, is_cR, st_ok,
                           r_lo, in_hi, r_hi, head_end, st_end);
    } else {
        run_pipeline<false>(lp, op, w01, w10, w11, ob, is_cL, is_cR, st_ok,
                            r_lo, in_hi, r_hi, head_end, st_end);
    }
}

extern "C" void kernel_launch(void* const* d_in, const int* in_sizes, int n_in,
                              void* d_out, int out_size, void* d_ws, size_t ws_size,
                              hipStream_t stream) {
    const float* x  = (const float*)d_in[0];
    const float* wt = (const float*)d_in[1];
    float* out = (float*)d_out;
    (void)d_ws; (void)ws_size;

    dim3 g(NWAVES), b(64);
    // all 20 steps in one launch
    diff20<<<g, b, 0, stream>>>(x, out, wt);
}

// Round 8
// 954.789 us; speedup vs baseline: 1.2322x; 1.2322x over previous
//
#include <hip/hip_runtime.h>

// DiffusionBlock: 20 steps of depthwise 3x3 stencil, reflect padding, on
// (16,2,1024,1024) fp32. Two launches of KF=10 fused steps.
//
// LDS-free register-rolling pipeline (5-point cross stencil: corner weights
// are exactly 0; w_l==w_r, w_t==w_b):
//   u_{s+1}[r] = w01*(u_s[r-1]+u_s[r+1]) + w10*(left+right) + w11*u_s[r]
// Each wave owns a 256-col swath (float4/lane), marches down rows keeping a
// 2-row register window per fused stage (20 NAMED float4 registers — never
// arrays; arrays get demoted to scratch). Horizontal halo via DPP
// wave_shr:1/wave_shl:1. Column mirror via per-lane cndmask; row mirror
// exact in gated head/tail phases.
//
// ROUND 8 = ROUND 7 RESUBMIT (round 7 never executed: "container failed
// twice" = infra flake; the same failure hit round 3 and that code ran when
// resubmitted in round 4. Code audit found no fault path: RB=32 phase/parity
// math re-verified, template split already compiled at 2x size in round 6).
// Theory unchanged: round-2 counters show KF=10 is LATENCY-bound (VALUBusy
// 63% @ occupancy 19%; 2/SIMD can't hide the 4-5cyc dependent chain).
// (a) RB 64->32: 5120 waves (~4-5/SIMD) at +24% row-halo redundancy;
// (b) FAST weight path (w11==0, w01==w10, validated round 6):
//     u' = (N+S+E+W)*0.25, 20->16 core VALU/stage.
// TRIPWIRE: WRITE_SIZE must stay ~131072 KB per dispatch.

#define IMG  1024
#define KF   10           // fused steps per launch
#define RB   32           // output rows per band (was 64; more waves)
#define LPAD 12           // left extension cols (>= KF, multiple of 4)
#define SW   232          // useful cols per swath
#define NSW  5            // 5*232 = 1160 >= 1024
#define NB   (IMG/RB)     // 32 bands
#define NPL  32           // planes = 16 batch * 2 ch
#define WPL  (NB*NSW)     // 160 waves per plane
#define NWAVES (NPL*WPL)  // 5120

__device__ __forceinline__ float dpp_left(float v) {   // lane i <- lane i-1 (wave_shr:1)
    return __int_as_float(__builtin_amdgcn_update_dpp(
        __float_as_int(v), __float_as_int(v), 0x138, 0xf, 0xf, false));
}
__device__ __forceinline__ float dpp_right(float v) {  // lane i <- lane i+1 (wave_shl:1)
    return __int_as_float(__builtin_amdgcn_update_dpp(
        __float_as_int(v), __float_as_int(v), 0x130, 0xf, 0xf, false));
}

// One fused stage: consumes C (= u_{j-1}[f+1]), bank OV (= u_{j-1}[f-1]),
// bank NV (= u_{j-1}[f]); produces u_j[f] into C, rotates OV <- old C.
// GEN=1 adds uniform activity gating + row-mirror patches (head/tail only).
// FAST (constexpr): weights are {w11==0, w01==w10} -> sum-of-4 * w01.
#define STAGE(jj, OV, NV, GEN)                                               \
    {                                                                        \
        float4 Cn; bool pr = true;                                           \
        const int f = _r - (jj);                                             \
        bool act = true;                                                     \
        if (GEN) {                                                           \
            const int lo = max(ob - KF + (jj), 0);                           \
            const int hi = min(ob + RB - 1 + KF - (jj), IMG - 1);            \
            act = (f >= lo) && (f <= hi);                                    \
        }                                                                    \
        if (act) {                                                           \
            const float4 mid = NV;                                           \
            float4 vs;                                                       \
            if (GEN && f == 0) {               /* u[-1] = u[1] = C */        \
                vs.x = C.x + C.x; vs.y = C.y + C.y;                          \
                vs.z = C.z + C.z; vs.w = C.w + C.w;                          \
            } else if (GEN && f == IMG - 1) {  /* u[N] = u[N-2] = OV */      \
                vs.x = OV.x + OV.x; vs.y = OV.y + OV.y;                      \
                vs.z = OV.z + OV.z; vs.w = OV.w + OV.w;                      \
            } else {                                                         \
                vs.x = OV.x + C.x; vs.y = OV.y + C.y;                        \
                vs.z = OV.z + C.z; vs.w = OV.w + C.w;                        \
            }                                                                \
            float lf = dpp_left(mid.w);                                      \
            float rg = dpp_right(mid.x);                                     \
            if (is_cL) lf = mid.y;             /* col 0: mirror col 1 */     \
            if (is_cR) rg = mid.z;             /* col 1023: mirror 1022 */   \
            const float h0 = lf    + mid.y;                                  \
            const float h1 = mid.x + mid.z;                                  \
            const float h2 = mid.y + mid.w;                                  \
            const float h3 = mid.z + rg;                                     \
            if constexpr (FAST) {                                            \
                Cn.x = (vs.x + h0) * w01;                                    \
                Cn.y = (vs.y + h1) * w01;                                    \
                Cn.z = (vs.z + h2) * w01;                                    \
                Cn.w = (vs.w + h3) * w01;                                    \
            } else {                                                         \
                Cn.x = vs.x*w01 + h0*w10 + mid.x*w11;                        \
                Cn.y = vs.y*w01 + h1*w10 + mid.y*w11;                        \
                Cn.z = vs.z*w01 + h2*w10 + mid.z*w11;                        \
                Cn.w = vs.w*w01 + h3*w10 + mid.w*w11;                        \
            }                                                                \
        } else { pr = false; Cn = C; }                                       \
        if (prod) { OV = C; }                                                \
        C = Cn; prod = GEN ? pr : true;                                      \
    }

// One pipeline advance at absolute input row rv. PF (p0/p1) holds row rv,
// reloaded with row rv+2. Bank names passed explicitly per stage.
#define STEPN(rv, PF, GEN, O0,N0,O1,N1,O2,N2,O3,N3,O4,N4,                    \
                           O5,N5,O6,N6,O7,N7,O8,N8,O9,N9)                    \
    do {                                                                     \
        const int _r = (rv);                                                 \
        float4 C = PF;                                                       \
        if (_r + 2 <= in_hi)                                                 \
            PF = *(const float4*)(lp + (size_t)(_r + 2) * IMG);              \
        bool prod = GEN ? (_r <= in_hi) : true;                              \
        STAGE(1,  O0, N0, GEN)                                               \
        STAGE(2,  O1, N1, GEN)                                               \
        STAGE(3,  O2, N2, GEN)                                               \
        STAGE(4,  O3, N3, GEN)                                               \
        STAGE(5,  O4, N4, GEN)                                               \
        STAGE(6,  O5, N5, GEN)                                               \
        STAGE(7,  O6, N6, GEN)                                               \
        STAGE(8,  O7, N7, GEN)                                               \
        STAGE(9,  O8, N8, GEN)                                               \
        STAGE(10, O9, N9, GEN)                                               \
        if ((!GEN || prod) && st_ok)                                         \
            *(float4*)(op + (size_t)(_r - KF) * IMG) = C;                    \
    } while (0)

#define STEP_E(rv, GEN) STEPN(rv, p0, GEN, a0,b0,a1,b1,a2,b2,a3,b3,a4,b4,    \
                                           a5,b5,a6,b6,a7,b7,a8,b8,a9,b9)
#define STEP_O(rv, GEN) STEPN(rv, p1, GEN, b0,a0,b1,a1,b2,a2,b3,a3,b4,a4,    \
                                           b5,a5,b6,a6,b7,a7,b8,a8,b9,a9)

template <bool FAST>
__device__ __forceinline__ void run_pipeline(
    const float* __restrict__ lp, float* __restrict__ op,
    float w01, float w10, float w11,
    int ob, bool is_cL, bool is_cR, bool st_ok,
    int r_lo, int in_hi, int r_hi, int head_end, int st_end)
{
    // 2-row banks for stages u_0..u_9 — NAMED registers (never an array).
    float4 a0{},a1{},a2{},a3{},a4{},a5{},a6{},a7{},a8{},a9{};
    float4 b0{},b1{},b2{},b3{},b4{},b5{},b6{},b7{},b8{},b9{};

    float4 p0, p1;                          // distance-2 row prefetch slots
    p0 = *(const float4*)(lp + (size_t)r_lo * IMG);
    p1 = *(const float4*)(lp + (size_t)(r_lo + 1) * IMG);

    // Phase lengths are all even and preserve the even/odd role alternation
    // (head = 2*KF iters; steady/tail lengths even for every band).
    // unroll(disable): bodies are already straight-line 10-stage blocks and
    // iterations are serially dependent — unrolling is pure code-size.
    #pragma clang loop unroll(disable)
    for (int r = r_lo; r <= head_end; r += 2) {
        STEP_E(r,     1);
        STEP_O(r + 1, 1);
    }
    #pragma clang loop unroll(disable)
    for (int r = head_end + 1; r <= st_end; r += 2) {
        STEP_E(r,     0);
        STEP_O(r + 1, 0);
    }
    #pragma clang loop unroll(disable)
    for (int r = st_end + 1; r <= r_hi; r += 2) {
        STEP_E(r,     1);
        STEP_O(r + 1, 1);
    }
}

__global__ __launch_bounds__(64, 4) void diff10(
    const float* __restrict__ src, float* __restrict__ dst,
    const float* __restrict__ wt)
{
    const int lane  = threadIdx.x;          // 64-thread block == one wave
    const int gw    = blockIdx.x;
    const int plane = gw / WPL;
    const int rem   = gw - plane * WPL;
    const int band  = rem / NSW;
    const int sw    = rem - band * NSW;

    const int ob  = band * RB;              // first output row of this band
    const int uc0 = sw * SW;                // first useful col of this swath
    const int c0  = uc0 - LPAD + 4 * lane;  // this lane's first col (may be <0)
    const int cld = min(max(c0, 0), IMG - 4); // clamped load col (garbage ok)

    const float* __restrict__ lp = src + (size_t)plane * IMG * IMG + cld;
    float* __restrict__       op = dst + (size_t)plane * IMG * IMG + cld;

    const float* w9 = wt + (size_t)(plane & 1) * 9;
    const float w01 = w9[1];   // vertical weight (== w9[7])
    const float w10 = w9[3];   // horizontal weight (== w9[5])
    const float w11 = w9[4];   // center weight (corners are 0)

    const bool is_cL  = (c0 == 0);          // lane's .x is image col 0
    const bool is_cR  = (c0 == IMG - 4);    // lane's .w is image col 1023
    const bool st_ok  = (c0 >= uc0) && (c0 < uc0 + SW) && (c0 <= IMG - 4);

    const int r_lo  = max(ob - KF, 0);
    const int in_hi = min(ob + RB - 1 + KF, IMG - 1);
    const int r_hi  = ob + RB - 1 + KF;     // last pipeline iteration
    const int head_end = r_lo + 2 * KF - 1; // generic head (2*KF steps, even)
    const int st_end   = min(r_hi, IMG - 1);// steady end; tail drains

    // Uniform specialization: actual weights have w11 == 0 (TAU=0.25,
    // H1=H2=1 -> 1-2hx-2hy = 0) and w01 == w10 == 0.25. Exact fp compare is
    // safe (values are exact pow-2 sums). Generic path kept as fallback.
    if (w11 == 0.0f && w01 == w10) {
        run_pipeline<true>(lp, op, w01, w10, w11, ob, is_cL, is_cR, st_ok,
                           r_lo, in_hi, r_hi, head_end, st_end);
    } else {
        run_pipeline<false>(lp, op, w01, w10, w11, ob, is_cL, is_cR, st_ok,
                            r_lo, in_hi, r_hi, head_end, st_end);
    }
}

extern "C" void kernel_launch(void* const* d_in, const int* in_sizes, int n_in,
                              void* d_out, int out_size, void* d_ws, size_t ws_size,
                              hipStream_t stream) {
    const float* x  = (const float*)d_in[0];
    const float* wt = (const float*)d_in[1];
    float* out = (float*)d_out;
    float* ws  = (float*)d_ws;   // needs >= 128 MiB (one tensor copy)

    dim3 g(NWAVES), b(64);
    // 20 steps = 2 launches x 10 fused steps
    diff10<<<g, b, 0, stream>>>(x,  ws,  wt);
    diff10<<<g, b, 0, stream>>>(ws, out, wt);
}

// Round 10
// 399.399 us; speedup vs baseline: 2.9456x; 2.3906x over previous
//
#include <hip/hip_runtime.h>

// DiffusionBlock: 20 steps of depthwise 3x3 stencil, reflect padding, on
// (16,2,1024,1024) fp32. Two launches of KF=10 fused steps.
//
// LDS-free register-rolling pipeline (5-point cross stencil: corner weights
// are exactly 0; w_l==w_r, w_t==w_b):
//   u_{s+1}[r] = w01*(u_s[r-1]+u_s[r+1]) + w10*(left+right) + w11*u_s[r]
// Each wave owns a 256-col swath (float4/lane), marches down rows keeping a
// 2-row register window per fused stage (20 NAMED float4 registers — never
// arrays; arrays get demoted to scratch). Horizontal halo via DPP
// wave_shr:1/wave_shl:1. Column mirror via per-lane cndmask; row mirror
// exact in gated head/tail phases.
//
// ROUND 10 (round 9 was an infra flake — its near-twin R8 ran): RB=32 +
// FAST + __launch_bounds__(64,2). Register model from rounds 1/2/5/6/8:
//   allocator VGPR cap = alignDown(256/min_waves, 8): 4->64, 3->80, 2->128
//   HW occupancy quantum: 4 waves/SIMD for any VGPR in 65..128 (m69)
// So (64,2) raises cap to 128 — fits banks(80)+temps(~30) with zero
// scratch AND zero AGPR-shuffle — while occupancy stays grid/HW-limited at
// 4/SIMD, unchanged vs (64,3). RB=32: 5120 waves -> 4 resident/SIMD hides
// the 4-5cyc dependent chain (R2: VALUBusy 63% @ 2.5 waves/SIMD). FAST
// (validated R6/R8): w11==0, w01==w10 -> u' = (N+S+E+W)*0.25.
// TRIPWIRE: WRITE_SIZE ~131072 KB/dispatch; VGPR_Count should be ~96-128.

#define IMG  1024
#define KF   10           // fused steps per launch
#define RB   32           // output rows per band
#define LPAD 12           // left extension cols (>= KF, multiple of 4)
#define SW   232          // useful cols per swath
#define NSW  5            // 5*232 = 1160 >= 1024
#define NB   (IMG/RB)     // 32 bands
#define NPL  32           // planes = 16 batch * 2 ch
#define WPL  (NB*NSW)     // 160 waves per plane
#define NWAVES (NPL*WPL)  // 5120

__device__ __forceinline__ float dpp_left(float v) {   // lane i <- lane i-1 (wave_shr:1)
    return __int_as_float(__builtin_amdgcn_update_dpp(
        __float_as_int(v), __float_as_int(v), 0x138, 0xf, 0xf, false));
}
__device__ __forceinline__ float dpp_right(float v) {  // lane i <- lane i+1 (wave_shl:1)
    return __int_as_float(__builtin_amdgcn_update_dpp(
        __float_as_int(v), __float_as_int(v), 0x130, 0xf, 0xf, false));
}

// One fused stage: consumes C (= u_{j-1}[f+1]), bank OV (= u_{j-1}[f-1]),
// bank NV (= u_{j-1}[f]); produces u_j[f] into C, rotates OV <- old C.
// GEN=1 adds uniform activity gating + row-mirror patches (head/tail only).
// FAST (constexpr): weights are {w11==0, w01==w10} -> sum-of-4 * w01.
#define STAGE(jj, OV, NV, GEN)                                               \
    {                                                                        \
        float4 Cn; bool pr = true;                                           \
        const int f = _r - (jj);                                             \
        bool act = true;                                                     \
        if (GEN) {                                                           \
            const int lo = max(ob - KF + (jj), 0);                           \
            const int hi = min(ob + RB - 1 + KF - (jj), IMG - 1);            \
            act = (f >= lo) && (f <= hi);                                    \
        }                                                                    \
        if (act) {                                                           \
            const float4 mid = NV;                                           \
            float4 vs;                                                       \
            if (GEN && f == 0) {               /* u[-1] = u[1] = C */        \
                vs.x = C.x + C.x; vs.y = C.y + C.y;                          \
                vs.z = C.z + C.z; vs.w = C.w + C.w;                          \
            } else if (GEN && f == IMG - 1) {  /* u[N] = u[N-2] = OV */      \
                vs.x = OV.x + OV.x; vs.y = OV.y + OV.y;                      \
                vs.z = OV.z + OV.z; vs.w = OV.w + OV.w;                      \
            } else {                                                         \
                vs.x = OV.x + C.x; vs.y = OV.y + C.y;                        \
                vs.z = OV.z + C.z; vs.w = OV.w + C.w;                        \
            }                                                                \
            float lf = dpp_left(mid.w);                                      \
            float rg = dpp_right(mid.x);                                     \
            if (is_cL) lf = mid.y;             /* col 0: mirror col 1 */     \
            if (is_cR) rg = mid.z;             /* col 1023: mirror 1022 */   \
            const float h0 = lf    + mid.y;                                  \
            const float h1 = mid.x + mid.z;                                  \
            const float h2 = mid.y + mid.w;                                  \
            const float h3 = mid.z + rg;                                     \
            if constexpr (FAST) {                                            \
                Cn.x = (vs.x + h0) * w01;                                    \
                Cn.y = (vs.y + h1) * w01;                                    \
                Cn.z = (vs.z + h2) * w01;                                    \
                Cn.w = (vs.w + h3) * w01;                                    \
            } else {                                                         \
                Cn.x = vs.x*w01 + h0*w10 + mid.x*w11;                        \
                Cn.y = vs.y*w01 + h1*w10 + mid.y*w11;                        \
                Cn.z = vs.z*w01 + h2*w10 + mid.z*w11;                        \
                Cn.w = vs.w*w01 + h3*w10 + mid.w*w11;                        \
            }                                                                \
        } else { pr = false; Cn = C; }                                       \
        if (prod) { OV = C; }                                                \
        C = Cn; prod = GEN ? pr : true;                                      \
    }

// One pipeline advance at absolute input row rv. PF (p0/p1) holds row rv,
// reloaded with row rv+2. Bank names passed explicitly per stage.
#define STEPN(rv, PF, GEN, O0,N0,O1,N1,O2,N2,O3,N3,O4,N4,                    \
                           O5,N5,O6,N6,O7,N7,O8,N8,O9,N9)                    \
    do {                                                                     \
        const int _r = (rv);                                                 \
        float4 C = PF;                                                       \
        if (_r + 2 <= in_hi)                                                 \
            PF = *(const float4*)(lp + (size_t)(_r + 2) * IMG);              \
        bool prod = GEN ? (_r <= in_hi) : true;                              \
        STAGE(1,  O0, N0, GEN)                                               \
        STAGE(2,  O1, N1, GEN)                                               \
        STAGE(3,  O2, N2, GEN)                                               \
        STAGE(4,  O3, N3, GEN)                                               \
        STAGE(5,  O4, N4, GEN)                                               \
        STAGE(6,  O5, N5, GEN)                                               \
        STAGE(7,  O6, N6, GEN)                                               \
        STAGE(8,  O7, N7, GEN)                                               \
        STAGE(9,  O8, N8, GEN)                                               \
        STAGE(10, O9, N9, GEN)                                               \
        if ((!GEN || prod) && st_ok)                                         \
            *(float4*)(op + (size_t)(_r - KF) * IMG) = C;                    \
    } while (0)

#define STEP_E(rv, GEN) STEPN(rv, p0, GEN, a0,b0,a1,b1,a2,b2,a3,b3,a4,b4,    \
                                           a5,b5,a6,b6,a7,b7,a8,b8,a9,b9)
#define STEP_O(rv, GEN) STEPN(rv, p1, GEN, b0,a0,b1,a1,b2,a2,b3,a3,b4,a4,    \
                                           b5,a5,b6,a6,b7,a7,b8,a8,b9,a9)

template <bool FAST>
__device__ __forceinline__ void run_pipeline(
    const float* __restrict__ lp, float* __restrict__ op,
    float w01, float w10, float w11,
    int ob, bool is_cL, bool is_cR, bool st_ok,
    int r_lo, int in_hi, int r_hi, int head_end, int st_end)
{
    // 2-row banks for stages u_0..u_9 — NAMED registers (never an array).
    float4 a0{},a1{},a2{},a3{},a4{},a5{},a6{},a7{},a8{},a9{};
    float4 b0{},b1{},b2{},b3{},b4{},b5{},b6{},b7{},b8{},b9{};

    float4 p0, p1;                          // distance-2 row prefetch slots
    p0 = *(const float4*)(lp + (size_t)r_lo * IMG);
    p1 = *(const float4*)(lp + (size_t)(r_lo + 1) * IMG);

    // Phase lengths are all even and preserve the even/odd role alternation:
    // head = 2*KF = 20 iters; steady = 32 (interior) / 22 (first, last);
    // tail = 0 (interior/first) / 10 (last band). All even.
    // unroll(disable): bodies are already straight-line 10-stage blocks and
    // iterations are serially dependent — unrolling is pure code-size.
    #pragma clang loop unroll(disable)
    for (int r = r_lo; r <= head_end; r += 2) {
        STEP_E(r,     1);
        STEP_O(r + 1, 1);
    }
    #pragma clang loop unroll(disable)
    for (int r = head_end + 1; r <= st_end; r += 2) {
        STEP_E(r,     0);
        STEP_O(r + 1, 0);
    }
    #pragma clang loop unroll(disable)
    for (int r = st_end + 1; r <= r_hi; r += 2) {
        STEP_E(r,     1);
        STEP_O(r + 1, 1);
    }
}

__global__ __launch_bounds__(64, 2) void diff10(
    const float* __restrict__ src, float* __restrict__ dst,
    const float* __restrict__ wt)
{
    const int lane  = threadIdx.x;          // 64-thread block == one wave
    const int gw    = blockIdx.x;
    const int plane = gw / WPL;
    const int rem   = gw - plane * WPL;
    const int band  = rem / NSW;
    const int sw    = rem - band * NSW;

    const int ob  = band * RB;              // first output row of this band
    const int uc0 = sw * SW;                // first useful col of this swath
    const int c0  = uc0 - LPAD + 4 * lane;  // this lane's first col (may be <0)
    const int cld = min(max(c0, 0), IMG - 4); // clamped load col (garbage ok)

    const float* __restrict__ lp = src + (size_t)plane * IMG * IMG + cld;
    float* __restrict__       op = dst + (size_t)plane * IMG * IMG + cld;

    const float* w9 = wt + (size_t)(plane & 1) * 9;
    const float w01 = w9[1];   // vertical weight (== w9[7])
    const float w10 = w9[3];   // horizontal weight (== w9[5])
    const float w11 = w9[4];   // center weight (corners are 0)

    const bool is_cL  = (c0 == 0);          // lane's .x is image col 0
    const bool is_cR  = (c0 == IMG - 4);    // lane's .w is image col 1023
    const bool st_ok  = (c0 >= uc0) && (c0 < uc0 + SW) && (c0 <= IMG - 4);

    const int r_lo  = max(ob - KF, 0);
    const int in_hi = min(ob + RB - 1 + KF, IMG - 1);
    const int r_hi  = ob + RB - 1 + KF;     // last pipeline iteration
    const int head_end = r_lo + 2 * KF - 1; // generic head (2*KF steps, even)
    const int st_end   = min(r_hi, IMG - 1);// steady end; tail drains

    // Uniform specialization: actual weights have w11 == 0 (TAU=0.25,
    // H1=H2=1 -> 1-2hx-2hy = 0) and w01 == w10 == 0.25. Exact fp compare is
    // safe (values are exact pow-2 sums). Generic path kept as fallback.
    if (w11 == 0.0f && w01 == w10) {
        run_pipeline<true>(lp, op, w01, w10, w11, ob, is_cL, is_cR, st_ok,
                           r_lo, in_hi, r_hi, head_end, st_end);
    } else {
        run_pipeline<false>(lp, op, w01, w10, w11, ob, is_cL, is_cR, st_ok,
                            r_lo, in_hi, r_hi, head_end, st_end);
    }
}

extern "C" void kernel_launch(void* const* d_in, const int* in_sizes, int n_in,
                              void* d_out, int out_size, void* d_ws, size_t ws_size,
                              hipStream_t stream) {
    const float* x  = (const float*)d_in[0];
    const float* wt = (const float*)d_in[1];
    float* out = (float*)d_out;
    float* ws  = (float*)d_ws;   // needs >= 128 MiB (one tensor copy)

    dim3 g(NWAVES), b(64);
    // 20 steps = 2 launches x 10 fused steps
    diff10<<<g, b, 0, stream>>>(x,  ws,  wt);
    diff10<<<g, b, 0, stream>>>(ws, out, wt);
}